// Round 8
// baseline (5349.484 us; speedup 1.0000x reference)
//
#include <hip/hip_runtime.h>

typedef _Float16 h2_t __attribute__((ext_vector_type(2)));

#define HID  100
#define TENC 4096
#define TDEC 4096
#define NCLS 6
#define NTHR 256   // 4 waves, one per SIMD

__device__ __forceinline__ float sigm(float v)  { return __builtin_amdgcn_rcpf(1.0f + __expf(-v)); }
__device__ __forceinline__ float tanh_(float v) { return 1.0f - 2.0f * __builtin_amdgcn_rcpf(1.0f + __expf(2.0f * v)); }

// lgkm-only barrier: does NOT drain vmcnt -> hsto global stores stay in flight.
#define SYNC_LDS() asm volatile("s_waitcnt lgkmcnt(0)\n\ts_barrier" ::: "memory")

__device__ __forceinline__ float packh2(float a, float b) {
    h2_t p; p[0] = (_Float16)a; p[1] = (_Float16)b;
    return __builtin_bit_cast(float, p);
}

// v5: SGPR h-broadcast. R7 post-mortem: step was split between DS-pipe
// occupancy (~50 ops: 28 b128 h-broadcast reads + 16 bpermute shuffles) and
// VALU issue. h is only 50 f16-pairs and UNIFORM -> belongs in SGPRs:
// one masked ds_read_b32 (lanes 0..49 load pair j) + 50 v_readlane pulls
// h into SGPRs; v_dot2_f32_f16 takes the SGPR directly as one operand.
// Layout: 4 waves x 25 cells; lane j<50 owns cell 25w+(j>>1), gate-pair j&1
// (rows cell+2gp*HID, cell+(2gp+1)*HID) over FULL k -> 2x50 = 100 packed
// regs (proven resident at VGPR_Count=116 in R7), no k-reduction.
// Gate exchange: activate locally (branchless tanh = 2*sigm(2v)-1, 6
// transcendentals/lane instead of 10), then 2 shfl_xor(.,1). c replicated
// in both lanes of the cell. Even lane writes h (LDS f16), odd lane writes
// decoder h history (global, never fenced). ONE lgkm-only barrier per step.
__global__ __launch_bounds__(NTHR, 1)
void lstm_rec(const float* __restrict__ x,      // [TENC*3]
              const int*   __restrict__ y,      // [TDEC]
              const float* __restrict__ eWih,   // [400*3]
              const float* __restrict__ eWhh,   // [400*HID]
              const float* __restrict__ ebih,
              const float* __restrict__ ebhh,
              const float* __restrict__ dWih,   // [400]
              const float* __restrict__ dWhh,
              const float* __restrict__ dbih,
              const float* __restrict__ dbhh,
              float* __restrict__ hsto)         // [(TDEC-1)*HID] decoder h history
{
    __shared__ __align__(16) _Float16 hbuf[2][112];   // [parity][100 used]
    __shared__ __align__(8)  uint2    xst[TENC];      // packed f16: {x0,x1},{x2,1}
    __shared__               unsigned yst[TDEC];      // packed f16: {yf,1}

    const int  t    = threadIdx.x;
    const int  w    = t >> 6;
    const int  j    = t & 63;
    const int  gp   = j & 1;                 // 0: gates i,f   1: gates g,o
    const int  cell = 25 * w + (j >> 1);
    const bool live = (j < 50);
    const int  jj   = live ? j : 0;          // safe ds_read index for idle lanes

    // branchless activation constants for gate slot 0 (i or g):
    // gp0: sigm(v) = 1*sigm(1*v)+0 ; gp1: tanh(v) = 2*sigm(2*v)-1
    const float asc = gp ? 2.0f : 1.0f;
    const float amul = gp ? 2.0f : 1.0f;
    const float aadd = gp ? -1.0f : 0.0f;

    // ---- stage x/y into LDS (f16-packed), zero h buffers ----
    for (int i = t; i < TENC; i += NTHR) {
        uint2 u;
        u.x = __builtin_bit_cast(unsigned, packh2(x[3*i], x[3*i+1]));
        u.y = __builtin_bit_cast(unsigned, packh2(x[3*i+2], 1.0f));
        xst[i] = u;
    }
    for (int i = t; i < TDEC; i += NTHR)
        yst[i] = __builtin_bit_cast(unsigned, packh2((float)y[i], 1.0f));
    if (t < 224) ((_Float16*)hbuf)[t] = (_Float16)0.0f;

    // ---- encoder weights: 2 full rows (k=0..99) as 50 packed pairs each ----
    float wf[2][50];
    float wx[2][2];                          // {Wih0,Wih1}, {Wih2, bias}
    float c = 0.0f;
    #pragma unroll
    for (int r = 0; r < 2; ++r) {
        #pragma unroll
        for (int k = 0; k < 50; ++k) wf[r][k] = 0.0f;
        wx[r][0] = wx[r][1] = 0.0f;
    }
    if (live) {
        #pragma unroll
        for (int r = 0; r < 2; ++r) {
            const int row = cell + (2 * gp + r) * HID;
            #pragma unroll
            for (int k = 0; k < 50; ++k)
                wf[r][k] = packh2(eWhh[row*HID + 2*k], eWhh[row*HID + 2*k + 1]);
            wx[r][0] = packh2(eWih[row*3+0], eWih[row*3+1]);
            wx[r][1] = packh2(eWih[row*3+2], ebih[row] + ebhh[row]);
        }
    }
    __syncthreads();   // covers staging

    int p = 0;

    // ================ encoder: 4096 steps ================
    for (int s = 0; s < TENC; ++s) {
        const float hp = ((const float*)&hbuf[p][0])[jj];   // pair j at lane j
        const uint2 xp = xst[s];
        const h2_t  x0 = __builtin_bit_cast(h2_t, xp.x);
        const h2_t  x1 = __builtin_bit_cast(h2_t, xp.y);

        float a0 = __builtin_amdgcn_fdot2(__builtin_bit_cast(h2_t, wx[0][0]), x0,
                   __builtin_amdgcn_fdot2(__builtin_bit_cast(h2_t, wx[0][1]), x1, 0.0f, false), false);
        float a1 = __builtin_amdgcn_fdot2(__builtin_bit_cast(h2_t, wx[1][0]), x0,
                   __builtin_amdgcn_fdot2(__builtin_bit_cast(h2_t, wx[1][1]), x1, 0.0f, false), false);

        const int hpi = __builtin_bit_cast(int, hp);
        #pragma unroll
        for (int k = 0; k < 50; ++k) {
            const h2_t hk = __builtin_bit_cast(h2_t, __builtin_amdgcn_readlane(hpi, k)); // SGPR broadcast
            a0 = __builtin_amdgcn_fdot2(__builtin_bit_cast(h2_t, wf[0][k]), hk, a0, false);
            a1 = __builtin_amdgcn_fdot2(__builtin_bit_cast(h2_t, wf[1][k]), hk, a1, false);
        }

        // local activation (branchless): slot0 = i (even) / g (odd); slot1 = f / o
        const float e0 = amul * sigm(asc * a0) + aadd;
        const float e1 = sigm(a1);
        const float q0 = __shfl_xor(e0, 1);
        const float q1 = __shfl_xor(e1, 1);
        const float fi = gp ? q0 : e0;
        const float ff = gp ? q1 : e1;
        const float fg = gp ? e0 : q0;
        const float fo = gp ? e1 : q1;
        c = ff * c + fi * fg;                 // replicated in the cell's two lanes
        const float hn = fo * tanh_(c);
        if (live && gp == 0) hbuf[p ^ 1][cell] = (_Float16)hn;
        SYNC_LDS();
        p ^= 1;
    }

    // ================ swap to decoder weights ================
    float wd[2];
    wd[0] = wd[1] = 0.0f;
    if (live) {
        #pragma unroll
        for (int r = 0; r < 2; ++r) {
            const int row = cell + (2 * gp + r) * HID;
            #pragma unroll
            for (int k = 0; k < 50; ++k)
                wf[r][k] = packh2(dWhh[row*HID + 2*k], dWhh[row*HID + 2*k + 1]);
            wd[r] = packh2(dWih[row], dbih[row] + dbhh[row]);
        }
    }

    // ================ decoder: 4095 steps (ratio==1 -> teacher-forced) ================
    for (int s = 0; s < TDEC - 1; ++s) {
        const float hp = ((const float*)&hbuf[p][0])[jj];
        const h2_t  yp = __builtin_bit_cast(h2_t, yst[s]);   // {yf, 1}

        float a0 = __builtin_amdgcn_fdot2(__builtin_bit_cast(h2_t, wd[0]), yp, 0.0f, false);
        float a1 = __builtin_amdgcn_fdot2(__builtin_bit_cast(h2_t, wd[1]), yp, 0.0f, false);

        const int hpi = __builtin_bit_cast(int, hp);
        #pragma unroll
        for (int k = 0; k < 50; ++k) {
            const h2_t hk = __builtin_bit_cast(h2_t, __builtin_amdgcn_readlane(hpi, k));
            a0 = __builtin_amdgcn_fdot2(__builtin_bit_cast(h2_t, wf[0][k]), hk, a0, false);
            a1 = __builtin_amdgcn_fdot2(__builtin_bit_cast(h2_t, wf[1][k]), hk, a1, false);
        }

        const float e0 = amul * sigm(asc * a0) + aadd;
        const float e1 = sigm(a1);
        const float q0 = __shfl_xor(e0, 1);
        const float q1 = __shfl_xor(e1, 1);
        const float fi = gp ? q0 : e0;
        const float ff = gp ? q1 : e1;
        const float fg = gp ? e0 : q0;
        const float fo = gp ? e1 : q1;
        c = ff * c + fi * fg;
        const float hn = fo * tanh_(c);
        if (live) {
            if (gp == 0) hbuf[p ^ 1][cell] = (_Float16)hn;   // LDS h for next step
            else         hsto[s * HID + cell] = hn;          // global history (unfenced)
        }
        SYNC_LDS();
        p ^= 1;
    }
}

// Parallel logits: out[t][r] = linW[r] . h_t + linb[r], last row zeroed.
__global__ __launch_bounds__(256)
void logits_k(const float* __restrict__ hsto, const float* __restrict__ linW,
              const float* __restrict__ linb, float* __restrict__ out)
{
    const int idx = blockIdx.x * 256 + threadIdx.x;
    if (idx >= TDEC * NCLS) return;
    const int tt = idx / NCLS;
    const int r  = idx % NCLS;
    if (tt >= TDEC - 1) { out[idx] = 0.0f; return; }
    const float* h  = hsto + tt * HID;
    const float* wr = linW + r * HID;
    float a = linb[r];
    #pragma unroll 4
    for (int k = 0; k < HID; ++k) a += wr[k] * h[k];
    out[idx] = a;
}

extern "C" void kernel_launch(void* const* d_in, const int* in_sizes, int n_in,
                              void* d_out, int out_size, void* d_ws, size_t ws_size,
                              hipStream_t stream)
{
    const float* x    = (const float*)d_in[0];
    const int*   y    = (const int*)  d_in[1];
    const float* eWih = (const float*)d_in[2];
    const float* eWhh = (const float*)d_in[3];
    const float* ebih = (const float*)d_in[4];
    const float* ebhh = (const float*)d_in[5];
    const float* dWih = (const float*)d_in[6];
    const float* dWhh = (const float*)d_in[7];
    const float* dbih = (const float*)d_in[8];
    const float* dbhh = (const float*)d_in[9];
    const float* linW = (const float*)d_in[10];
    const float* linb = (const float*)d_in[11];
    float* out  = (float*)d_out;
    float* hsto = (float*)d_ws;   // (TDEC-1)*HID*4 = 1.64 MB scratch

    lstm_rec<<<dim3(1), dim3(NTHR), 0, stream>>>(
        x, y, eWih, eWhh, ebih, ebhh, dWih, dWhh, dbih, dbhh, hsto);

    const int nout = TDEC * NCLS;
    logits_k<<<dim3((nout + 255) / 256), dim3(256), 0, stream>>>(hsto, linW, linb, out);
}

// Round 9
// 4980.819 us; speedup vs baseline: 1.0740x; 1.0740x over previous
//
#include <hip/hip_runtime.h>

typedef _Float16 h2_t __attribute__((ext_vector_type(2)));

#define HID  100
#define TENC 4096
#define TDEC 4096
#define NCLS 6
#define NSTEP (TENC + TDEC - 1)   // 8191 gate-input rows
#define NTHR 256                  // 4 waves, one per SIMD

__device__ __forceinline__ float sigm(float v)  { return __builtin_amdgcn_rcpf(1.0f + __expf(-v)); }
__device__ __forceinline__ float tanh_(float v) { return 1.0f - 2.0f * __builtin_amdgcn_rcpf(1.0f + __expf(2.0f * v)); }

// lgkm-only barrier: does NOT drain vmcnt -> gx prefetch loads + hsto stores
// stay in flight across steps.
#define SYNC_LDS() asm volatile("s_waitcnt lgkmcnt(0)\n\ts_barrier" ::: "memory")

__device__ __forceinline__ float packh2(float a, float b) {
    h2_t p; p[0] = (_Float16)a; p[1] = (_Float16)b;
    return __builtin_bit_cast(float, p);
}

// Precompute gate-input streams: gxs[st][cell] = 4 gates (i,f,g,o) of
// (Wih @ input_st + bih + bhh), packed 4 x f16 = uint2.
// st < TENC: encoder (input = x[st]); st >= TENC: decoder step st-TENC
// (input = y[st-TENC]; teacher_forcing_ratio==1 -> always the label).
__global__ __launch_bounds__(256)
void gx_k(const float* __restrict__ x, const int* __restrict__ y,
          const float* __restrict__ eWih, const float* __restrict__ ebih,
          const float* __restrict__ ebhh, const float* __restrict__ dWih,
          const float* __restrict__ dbih, const float* __restrict__ dbhh,
          uint2* __restrict__ gxs)
{
    const int idx = blockIdx.x * 256 + threadIdx.x;
    if (idx >= NSTEP * HID) return;
    const int st   = idx / HID;
    const int cell = idx - st * HID;
    float g[4];
    if (st < TENC) {
        const float x0 = x[3*st], x1 = x[3*st+1], x2 = x[3*st+2];
        #pragma unroll
        for (int r = 0; r < 4; ++r) {
            const int row = cell + r * HID;
            g[r] = eWih[row*3]*x0 + eWih[row*3+1]*x1 + eWih[row*3+2]*x2
                 + ebih[row] + ebhh[row];
        }
    } else {
        const float yf = (float)y[st - TENC];
        #pragma unroll
        for (int r = 0; r < 4; ++r) {
            const int row = cell + r * HID;
            g[r] = dWih[row]*yf + dbih[row] + dbhh[row];
        }
    }
    uint2 u;
    u.x = __builtin_bit_cast(unsigned, packh2(g[0], g[1]));
    u.y = __builtin_bit_cast(unsigned, packh2(g[2], g[3]));
    gxs[idx] = u;
}

// v6 = R7 (best: 1217 cyc/step) + precomputed gx streams + parity-unrolled
// loop. 4 waves; lane l: ci=l&31, half=l>>5, cell=w*32+ci (2 lanes per cell).
// Lane holds 4 gate rows x its k-half = 4x25 packed-f16 pairs (100 VGPRs,
// proven resident). Step: 7 DS reads (h half) -> 100 fdot2 -> half1 folds
// its prefetched gx (global pipe, 1 step ahead) -> 4 shfl_xor(32) k-reduction
// -> both halves activate redundantly (c replicated) -> half0 writes h f16
// to LDS, half1 writes decoder h history to global (unfenced) -> ONE
// lgkm-only barrier. R8 lesson: broadcasts must ride DS (readlane = VALU).
__global__ __launch_bounds__(NTHR, 1)
void lstm_rec(const float* __restrict__ eWhh,   // [400*HID]
              const float* __restrict__ dWhh,   // [400*HID]
              const uint2* __restrict__ gxs,    // [NSTEP+1][HID] (padded row)
              float* __restrict__ hsto)         // [(TDEC-1)*HID]
{
    __shared__ __align__(16) _Float16 hbuf[2][2][64];  // [parity][k-half][50 used]

    const int  t    = threadIdx.x;
    const int  w    = t >> 6;
    const int  l    = t & 63;
    const int  ci   = l & 31;
    const int  half = l >> 5;
    const int  cell = w * 32 + ci;
    const bool live = (cell < HID);
    const bool gldr = live && (half == 1);   // gx loader / hsto writer lanes
    const int  k0   = half * 50;

    float wf[4][25];
    float c = 0.0f;

    if (t < 256) ((_Float16*)hbuf)[t] = (_Float16)0.0f;

    #pragma unroll
    for (int r = 0; r < 4; ++r)
        #pragma unroll
        for (int j = 0; j < 25; ++j) wf[r][j] = 0.0f;
    if (live) {
        #pragma unroll
        for (int r = 0; r < 4; ++r) {
            const int row = cell + r * HID;
            #pragma unroll
            for (int j = 0; j < 25; ++j)
                wf[r][j] = packh2(eWhh[row*HID + k0 + 2*j], eWhh[row*HID + k0 + 2*j + 1]);
        }
    }
    __syncthreads();

    uint2 gcur = gldr ? gxs[cell] : make_uint2(0u, 0u);   // gx for step 0

    // One LSTM step: read h[parity pin], write h[parity pin^1].
    // gnext index passed in; gcur used post-dots (full dot phase of slack).
    #define STEP_BODY(pin, gnext_idx, do_hsto, hsto_idx)                          \
    {                                                                             \
        const float4* h4 = (const float4*)&hbuf[pin][half][0];                    \
        float hp[25];                                                             \
        _Pragma("unroll")                                                         \
        for (int j = 0; j < 6; ++j) {                                             \
            const float4 v = h4[j];                                               \
            hp[4*j+0] = v.x; hp[4*j+1] = v.y; hp[4*j+2] = v.z; hp[4*j+3] = v.w;   \
        }                                                                         \
        hp[24] = ((const float*)h4)[24];                                          \
        uint2 gnew = gldr ? gxs[(gnext_idx)] : make_uint2(0u, 0u);                \
        float a0 = 0.f, a1 = 0.f, a2 = 0.f, a3 = 0.f;                             \
        _Pragma("unroll")                                                         \
        for (int j = 0; j < 25; ++j) {                                            \
            const h2_t hh = __builtin_bit_cast(h2_t, hp[j]);                      \
            a0 = __builtin_amdgcn_fdot2(__builtin_bit_cast(h2_t, wf[0][j]), hh, a0, false); \
            a1 = __builtin_amdgcn_fdot2(__builtin_bit_cast(h2_t, wf[1][j]), hh, a1, false); \
            a2 = __builtin_amdgcn_fdot2(__builtin_bit_cast(h2_t, wf[2][j]), hh, a2, false); \
            a3 = __builtin_amdgcn_fdot2(__builtin_bit_cast(h2_t, wf[3][j]), hh, a3, false); \
        }                                                                         \
        if (half == 1) {                                                          \
            const h2_t g01 = __builtin_bit_cast(h2_t, gcur.x);                    \
            const h2_t g23 = __builtin_bit_cast(h2_t, gcur.y);                    \
            a0 += (float)g01[0]; a1 += (float)g01[1];                             \
            a2 += (float)g23[0]; a3 += (float)g23[1];                             \
        }                                                                         \
        gcur = gnew;                                                              \
        a0 += __shfl_xor(a0, 32);                                                 \
        a1 += __shfl_xor(a1, 32);                                                 \
        a2 += __shfl_xor(a2, 32);                                                 \
        a3 += __shfl_xor(a3, 32);                                                 \
        const float fi = sigm(a0), ff = sigm(a1), fg = tanh_(a2), fo = sigm(a3);  \
        c = ff * c + fi * fg;                                                     \
        const float hn = fo * tanh_(c);                                           \
        if (live && half == 0) {                                                  \
            const int hh2 = (cell < 50) ? 1 : 0;  /* cell<50 -> buf 0 */          \
            hbuf[pin ^ 1][1 - hh2][cell - 50*(1-hh2)] = (_Float16)hn;             \
        }                                                                         \
        if (do_hsto && gldr) hsto[(hsto_idx) * HID + cell] = hn;                  \
        SYNC_LDS();                                                               \
    }

    // ================ encoder: 4096 steps, parity-unrolled x2 ================
    for (int s = 0; s < TENC; s += 2) {
        STEP_BODY(0, (s + 1) * HID + cell, false, 0);
        STEP_BODY(1, (s + 2) * HID + cell, false, 0);
    }
    // encoder ends at parity 0; gcur already holds gxs[TENC] = decoder step 0.

    // ================ swap to decoder weights ================
    if (live) {
        #pragma unroll
        for (int r = 0; r < 4; ++r) {
            const int row = cell + r * HID;
            #pragma unroll
            for (int j = 0; j < 25; ++j)
                wf[r][j] = packh2(dWhh[row*HID + k0 + 2*j], dWhh[row*HID + k0 + 2*j + 1]);
        }
    }
    // no barrier needed: decoder step 0 reads hbuf[0], which is stable.

    // ================ decoder: 4095 steps (4094 paired + 1 tail) ================
    for (int s = 0; s < TDEC - 2; s += 2) {
        STEP_BODY(0, (TENC + s + 1) * HID + cell, true, s);
        STEP_BODY(1, (TENC + s + 2) * HID + cell, true, s + 1);
    }
    // tail step s = TDEC-2 (prefetch hits the padded row NSTEP, discarded)
    STEP_BODY(0, NSTEP * HID + cell, true, TDEC - 2);

    #undef STEP_BODY
}

// Parallel logits: out[t][r] = linW[r] . h_t + linb[r], last row zeroed.
__global__ __launch_bounds__(256)
void logits_k(const float* __restrict__ hsto, const float* __restrict__ linW,
              const float* __restrict__ linb, float* __restrict__ out)
{
    const int idx = blockIdx.x * 256 + threadIdx.x;
    if (idx >= TDEC * NCLS) return;
    const int tt = idx / NCLS;
    const int r  = idx % NCLS;
    if (tt >= TDEC - 1) { out[idx] = 0.0f; return; }
    const float* h  = hsto + tt * HID;
    const float* wr = linW + r * HID;
    float a = linb[r];
    #pragma unroll 4
    for (int k = 0; k < HID; ++k) a += wr[k] * h[k];
    out[idx] = a;
}

extern "C" void kernel_launch(void* const* d_in, const int* in_sizes, int n_in,
                              void* d_out, int out_size, void* d_ws, size_t ws_size,
                              hipStream_t stream)
{
    const float* x    = (const float*)d_in[0];
    const int*   y    = (const int*)  d_in[1];
    const float* eWih = (const float*)d_in[2];
    const float* eWhh = (const float*)d_in[3];
    const float* ebih = (const float*)d_in[4];
    const float* ebhh = (const float*)d_in[5];
    const float* dWih = (const float*)d_in[6];
    const float* dWhh = (const float*)d_in[7];
    const float* dbih = (const float*)d_in[8];
    const float* dbhh = (const float*)d_in[9];
    const float* linW = (const float*)d_in[10];
    const float* linb = (const float*)d_in[11];
    float* out  = (float*)d_out;

    float* hsto = (float*)d_ws;                                   // 1.64 MB
    uint2* gxs  = (uint2*)((char*)d_ws + (2u << 20));             // (NSTEP+1)*HID*8 = 6.56 MB

    const int ngx = NSTEP * HID;
    gx_k<<<dim3((ngx + 255) / 256), dim3(256), 0, stream>>>(
        x, y, eWih, ebih, ebhh, dWih, dbih, dbhh, gxs);

    lstm_rec<<<dim3(1), dim3(NTHR), 0, stream>>>(eWhh, dWhh, gxs, hsto);

    const int nout = TDEC * NCLS;
    logits_k<<<dim3((nout + 255) / 256), dim3(256), 0, stream>>>(hsto, linW, linb, out);
}